// Round 8
// baseline (1931.725 us; speedup 1.0000x reference)
//
#include <hip/hip_runtime.h>
#include <hip/hip_bf16.h>

// LSTM B=1024 T=256 IN=64 H=512. Round 13: occupancy fix vs R9 (1714us).
// R9 counter arithmetic: step 6.8us = 2.2us VALU + 1.0us MFMA + 3.6us STALL,
// with exactly 1 wave/SIMD (256 thr, 1 block/CU) -> every ds_read->MFMA dep,
// epilogue dep-chain and exchange rtt is fully exposed. R10 (2 blocks/CU)
// failed for a different reason: phase-locked cadence + doubled per-CU
// staging/weights. This round keeps ONE block per CU (per-CU work, staging,
// flag fan-in unchanged) but makes it 512 threads = 8 waves = 2 waves/SIMD:
// each wave takes ONE n-tile (R10's proven per-wave layout: bfr[36]=144
// VGPR, 16-iter epilogue, ~230 VGPR < 256 so both waves fit per SIMD).
// Correlated exchange waits stay, but micro-stalls + serialized VALU/MFMA
// issue now interleave across co-waves: step ~ max(3.2us issue, ~3.6us
// critical path) instead of their sum. Also reverts R12's atomic-exchange
// (clean null: identical FETCH/WRITE) to plain agent-scope stores.
// Protocol unchanged from R9: per-wave release flags (now 64/group = 8 jb x
// 8 waves, one 256B region; all 64 lanes poll one flag each), drain own
// stores -> publish own flag, poll-pass is the LDS-reuse token, one
// syncthreads/step, 3-buffer h rotation (skew<=1 safe), poll watchdog.

#define TST   256
#define BATCH 1024
#define HID   512
#define INSZ  64
#define NCLS  10
#define LDSTR 584   // elem stride: 1168 B = 292 dw = 4 mod 32 -> conflict-free

typedef _Float16 f16x8  __attribute__((ext_vector_type(8)));
typedef float    f32x16 __attribute__((ext_vector_type(16)));
typedef unsigned long long u64;

__device__ __forceinline__ float fast_rcp(float x) {
    return __builtin_amdgcn_rcpf(x);   // v_rcp_f32, ~1 ulp
}

__device__ __forceinline__ float tanh_f(float x) {
    return 2.0f * fast_rcp(1.0f + __expf(-2.0f * x)) - 1.0f;
}

__device__ __forceinline__ f16x8 cvt8(float4 a, float4 b) {
    f16x8 o;
    o[0] = (_Float16)a.x; o[1] = (_Float16)a.y; o[2] = (_Float16)a.z; o[3] = (_Float16)a.w;
    o[4] = (_Float16)b.x; o[5] = (_Float16)b.y; o[6] = (_Float16)b.z; o[7] = (_Float16)b.w;
    return o;
}

__device__ __forceinline__ u64 cvt4_u64(float4 a) {
    _Float16 h[4] = {(_Float16)a.x, (_Float16)a.y, (_Float16)a.z, (_Float16)a.w};
    u64 r;
    __builtin_memcpy(&r, h, 8);
    return r;
}

template <int CTRL>
__device__ __forceinline__ float dpp_f(float v) {
    return __builtin_bit_cast(float,
        __builtin_amdgcn_mov_dpp(__builtin_bit_cast(int, v), CTRL, 0xF, 0xF, true));
}
template <int CTRL>
__device__ __forceinline__ unsigned dpp_u(unsigned v) {
    return (unsigned)__builtin_amdgcn_mov_dpp((int)v, CTRL, 0xF, 0xF, true);
}
// DPP ctrls: quad_perm xor1=0xB1, xor2=0x4E, xor3=0x1B (symmetric);
// row_shl:4=0x104, row_shl:8=0x108 (dst lane i <- src lane i+N).

__global__ __launch_bounds__(512, 1) void lstm_persist(
    const float* __restrict__ x,   const float* __restrict__ h0,
    const float* __restrict__ c0,  const float* __restrict__ Wih,
    const float* __restrict__ Whh, const float* __restrict__ bih,
    const float* __restrict__ bhh, _Float16* __restrict__ hb,
    unsigned* __restrict__ bar)
{
    __shared__ __align__(16) _Float16 As[32][LDSTR];   // 37376 B

    const int tid   = threadIdx.x;
    const int lane  = tid & 63;
    const int w     = tid >> 6;        // wave 0..7
    const int l31   = lane & 31;
    const int khalf = (lane >> 5) * 8;
    const int g  = (int)(blockIdx.x >> 3);   // m-group 0..31
    const int jb = (int)(blockIdx.x & 7);    // j-block 0..7
    const int m0 = g * 32;
    const int j0 = jb * 64;
    // 64 per-wave release flags per group (8 jb x 8 waves, 4B apart =
    // one 256B region). 8KB total, memset 0.
    unsigned* flg = bar + g * 64;

    // Wave owns 32 n-rows: 8 jcols x 4 gates (R10's proven layout).
    const int gate = l31 & 3;
    const int jcol = j0 + w * 8 + (l31 >> 2);
    const int nrow = gate * HID + jcol;

    // ---- B fragments in registers (one-time): bfr[kt], 144 VGPRs ----
    f16x8 bfr[36];
    #pragma unroll
    for (int kt = 0; kt < 36; ++kt) {
        const int k0 = kt * 16 + khalf;
        const float* p = (kt < 32) ? (Whh + (size_t)nrow * HID + k0)
                                   : (Wih + (size_t)nrow * INSZ + (k0 - HID));
        float4 f0 = ((const float4*)p)[0];
        float4 f1 = ((const float4*)p)[1];
        bfr[kt] = cvt8(f0, f1);
    }
    const float bsv = bih[nrow] + bhh[nrow];
    const float s   = (gate == 2) ? 2.0f : 1.0f;   // tanh for g, sigmoid otherwise
    const int rowhi = (lane >> 5) * 4;

    // ---- c state in registers (all 4 quad lanes share (row,jcol)) ----
    float cr[16];
    #pragma unroll
    for (int r = 0; r < 16; ++r) {
        int row = (r & 3) + 8 * (r >> 2) + rowhi;
        cr[r] = c0[(size_t)(m0 + row) * HID + jcol];
    }

    const int rr = tid >> 4;       // staging: 16 threads per row (32 rows)
    const int q  = tid & 15;

    for (int t = 0; t < TST; ++t) {
        const _Float16* rb = hb + (size_t)((t + 2) % 3) * (BATCH * HID);
        _Float16*       wb = hb + (size_t)(t % 3) * (BATCH * HID);

        // ---- issue x load first: its latency hides under the flag poll ----
        float4 x0;
        {
            const float* xp = x + (size_t)(m0 + rr) * (TST * INSZ) + t * INSZ + q * 4;
            x0 = ((const float4*)xp)[0];
        }
        if (t == 0) {
            u64 hv[8];
            #pragma unroll
            for (int u = 0; u < 8; ++u) {
                float4 f = *(const float4*)(h0 + (size_t)(m0 + rr) * HID + q * 4 + u * 64);
                hv[u] = cvt4_u64(f);
            }
            #pragma unroll
            for (int u = 0; u < 8; ++u)
                *(u64*)&As[rr][q * 4 + u * 64] = hv[u];
        } else {
            // ---- poll: all 64 lanes watch one (jb,w) wave flag each.
            // Waves set flag = t at the end of step t-1. Watchdog: 2^14
            // spins so a latent sync bug surfaces as a wrong answer, never
            // a wedged container.
            const unsigned tgt = (unsigned)t;
            int spins = 0;
            while (true) {
                unsigned v = __hip_atomic_load(flg + lane,
                                               __ATOMIC_RELAXED, __HIP_MEMORY_SCOPE_AGENT);
                if (__all((int)(v >= tgt))) break;
                if (++spins > (1 << 14)) break;   // watchdog (never in practice)
                __builtin_amdgcn_s_sleep(1);
            }
            __atomic_signal_fence(__ATOMIC_SEQ_CST);  // compiler fence: no hoist/sink
            // coherent (sc0 sc1) 8B loads — data was acked at the coherence
            // point before each producer wave's flag was set.
            const u64* rbq = (const u64*)(rb + (size_t)(m0 + rr) * HID);
            u64 hv[8];
            #pragma unroll
            for (int u = 0; u < 8; ++u)
                hv[u] = __hip_atomic_load(&rbq[q + u * 16],
                                          __ATOMIC_RELAXED, __HIP_MEMORY_SCOPE_AGENT);
            #pragma unroll
            for (int u = 0; u < 8; ++u)
                *(u64*)&As[rr][q * 4 + u * 64] = hv[u];
        }
        *(u64*)&As[rr][512 + q * 4] = cvt4_u64(x0);   // x_t -> k 512..575
        __syncthreads();   // staging join (the only barrier per step)

        // ---- MFMA: 36 k-tiles, single n-tile per wave ----
        f32x16 acc;
        #pragma unroll
        for (int i = 0; i < 16; ++i) acc[i] = 0.0f;
        #pragma unroll
        for (int kt = 0; kt < 36; ++kt) {
            f16x8 af = *(const f16x8*)&As[l31][kt * 16 + khalf];
            acc = __builtin_amdgcn_mfma_f32_32x32x16_f16(af, bfr[kt], acc, 0, 0, 0);
        }

        // ---- epilogue: DPP gate combine (VALU, no DS), c/h update, 8B stores ----
        #pragma unroll
        for (int r = 0; r < 16; ++r) {
            float v = acc[r] + bsv;
            float e = __expf(-s * v);
            float act = s * fast_rcp(1.0f + e) - (s - 1.0f);   // sigmoid or tanh
            float fu = dpp_f<0xB1>(act);   // quad xor1: f
            float gu = dpp_f<0x4E>(act);   // quad xor2: g
            float ou = dpp_f<0x1B>(act);   // quad xor3: o
            float cn = fu * cr[r] + act * gu;
            cr[r] = cn;
            float hn = ou * tanh_f(cn);
            unsigned hu = (unsigned)__builtin_bit_cast(unsigned short, (_Float16)hn);
            unsigned pk = hu | (dpp_u<0x104>(hu) << 16);          // <- lane+4
            u64 v4 = (u64)pk | ((u64)dpp_u<0x108>(pk) << 32);     // <- lane+8
            if ((l31 & 15) == 0) {
                int row = (r & 3) + 8 * (r >> 2) + rowhi;
                __hip_atomic_store((u64*)&wb[(size_t)(m0 + row) * HID + jcol],
                                   v4, __ATOMIC_RELAXED, __HIP_MEMORY_SCOPE_AGENT);
            }
        }

        // ---- per-wave release: drain own stores, publish own flag.
        // No block barrier: the poll (all 64 flags >= t+1) is the LDS-reuse
        // token for the next iteration's staging writes. ----
        asm volatile("s_waitcnt vmcnt(0)" ::: "memory");
        if (lane == 0)
            __hip_atomic_store(flg + (jb * 8 + w), (unsigned)(t + 1),
                               __ATOMIC_RELAXED, __HIP_MEMORY_SCOPE_AGENT);
    }
}

// ---------------- final linear: preds = hT @ W_lin^T + b_lin ----------------
__global__ __launch_bounds__(256) void final_kernel(
    const _Float16* __restrict__ h, const float* __restrict__ Wl,
    const float* __restrict__ bl, float* __restrict__ out)
{
    int i = blockIdx.x * 256 + threadIdx.x;
    if (i >= BATCH * NCLS) return;
    int b = i / NCLS, c = i - b * NCLS;
    const f16x8* hp = (const f16x8*)(h + (size_t)b * HID);
    const float4* wp = (const float4*)(Wl + (size_t)c * HID);
    float sacc = bl[c];
    #pragma unroll 4
    for (int k8 = 0; k8 < HID / 8; ++k8) {
        f16x8 hv = hp[k8];
        float4 w0 = wp[2 * k8], w1 = wp[2 * k8 + 1];
        sacc += (float)hv[0] * w0.x + (float)hv[1] * w0.y +
                (float)hv[2] * w0.z + (float)hv[3] * w0.w +
                (float)hv[4] * w1.x + (float)hv[5] * w1.y +
                (float)hv[6] * w1.z + (float)hv[7] * w1.w;
    }
    out[i] = sacc;
}

extern "C" void kernel_launch(void* const* d_in, const int* in_sizes, int n_in,
                              void* d_out, int out_size, void* d_ws, size_t ws_size,
                              hipStream_t stream)
{
    const float* x    = (const float*)d_in[0];
    const float* h0   = (const float*)d_in[1];
    const float* c0   = (const float*)d_in[2];
    const float* Wih  = (const float*)d_in[3];
    const float* Whh  = (const float*)d_in[4];
    const float* bih  = (const float*)d_in[5];
    const float* bhh  = (const float*)d_in[6];
    const float* Wlin = (const float*)d_in[7];
    const float* blin = (const float*)d_in[8];
    float* out = (float*)d_out;

    unsigned* bar = (unsigned*)d_ws;                   // 32 groups x 64 wave-flags
    _Float16* hb  = (_Float16*)((char*)d_ws + 8192);   // 3 x 1 MB h buffers

    hipMemsetAsync(d_ws, 0, 8192, stream);             // zero release flags

    // 256 blocks x 512 threads: 1 block/CU, 8 waves = 2 waves/SIMD so
    // co-waves hide each other's dep stalls; per-CU staging/weights/flag
    // fan-in unchanged vs R9.
    lstm_persist<<<256, 512, 0, stream>>>(x, h0, c0, Wih, Whh, bih, bhh, hb, bar);

    // step t=255 wrote buffer (255 % 3) == 0 -> hb
    final_kernel<<<(BATCH * NCLS + 255) / 256, 256, 0, stream>>>(hb, Wlin, blin, out);
}